// Round 5
// baseline (120.537 us; speedup 1.0000x reference)
//
#include <hip/hip_runtime.h>

#define OC 1024
#define ICN 1024
#define KK 9
#define NELEM (OC * ICN * KK)
#define CH (ICN * KK)      // 9216 floats per channel
#define CH4 (CH / 4)       // 2304 float4
#define BT 512             // 8 waves/block, 4 blocks/CU
#define KMB 2048           // kmax blocks

// ---------------- K1: per-block partial max (no atomics) --------------------
// 2048 blocks x 256 thr = 524288 threads; 4 float4 each + first 262144 a 5th.
// 8 blocks/CU x 4 waves = 32 waves/CU; all loads coalesced dwordx4.
__global__ void __launch_bounds__(256, 8) kmax_part(const float* __restrict__ x,
                                                    float* __restrict__ part) {
    __shared__ float s_m[4];
    const int tid = blockIdx.x * 256 + threadIdx.x;
    const int stride = KMB * 256;  // 524288 float4
    const float4* x4 = (const float4*)x;
    float4 v0 = x4[tid];
    float4 v1 = x4[tid + stride];
    float4 v2 = x4[tid + 2 * stride];
    float4 v3 = x4[tid + 3 * stride];
    float m = 0.f;
    if (tid < (CH4 * OC - 4 * stride)) {           // 262144 tail float4s
        float4 v4 = x4[tid + 4 * stride];
        m = fmaxf(fmaxf(fabsf(v4.x), fabsf(v4.y)), fmaxf(fabsf(v4.z), fabsf(v4.w)));
    }
    m = fmaxf(m, fmaxf(fmaxf(fabsf(v0.x), fabsf(v0.y)), fmaxf(fabsf(v0.z), fabsf(v0.w))));
    m = fmaxf(m, fmaxf(fmaxf(fabsf(v1.x), fabsf(v1.y)), fmaxf(fabsf(v1.z), fabsf(v1.w))));
    m = fmaxf(m, fmaxf(fmaxf(fabsf(v2.x), fabsf(v2.y)), fmaxf(fabsf(v2.z), fabsf(v2.w))));
    m = fmaxf(m, fmaxf(fmaxf(fabsf(v3.x), fabsf(v3.y)), fmaxf(fabsf(v3.z), fabsf(v3.w))));
    #pragma unroll
    for (int off = 32; off > 0; off >>= 1)
        m = fmaxf(m, __shfl_xor(m, off, 64));
    if ((threadIdx.x & 63) == 0) s_m[threadIdx.x >> 6] = m;
    __syncthreads();
    if (threadIdx.x == 0)
        part[blockIdx.x] = fmaxf(fmaxf(s_m[0], s_m[1]), fmaxf(s_m[2], s_m[3]));
}

__global__ void __launch_bounds__(256) kmax_atomic(const float* __restrict__ x,
                                                   unsigned* __restrict__ ws) {
    __shared__ float s_m[4];
    const int tid = blockIdx.x * 256 + threadIdx.x;
    const int stride = KMB * 256;
    const float4* x4 = (const float4*)x;
    float m = 0.f;
    #pragma unroll
    for (int k = 0; k < 4; ++k) {
        float4 v = x4[tid + k * stride];
        m = fmaxf(m, fmaxf(fmaxf(fabsf(v.x), fabsf(v.y)), fmaxf(fabsf(v.z), fabsf(v.w))));
    }
    if (tid < (CH4 * OC - 4 * stride)) {
        float4 v = x4[tid + 4 * stride];
        m = fmaxf(m, fmaxf(fmaxf(fabsf(v.x), fabsf(v.y)), fmaxf(fabsf(v.z), fabsf(v.w))));
    }
    #pragma unroll
    for (int off = 32; off > 0; off >>= 1)
        m = fmaxf(m, __shfl_xor(m, off, 64));
    if ((threadIdx.x & 63) == 0) s_m[threadIdx.x >> 6] = m;
    __syncthreads();
    if (threadIdx.x == 0) {
        m = fmaxf(fmaxf(s_m[0], s_m[1]), fmaxf(s_m[2], s_m[3]));
        atomicMax(ws, __float_as_uint(m));
    }
}

// ---------------- K2: LDS-staged quant + stage1 + stage2 --------------------
// One 36 KB LDS buffer, reused: (a) float x-stage, (b) overlaid s16 quant
// values [0,18K) + res [18K,22K) + prio [22K,26K) + meta [26K,30K).
// All global traffic coalesced float4. 4 blocks/CU, 32 waves/CU.
__global__ void __launch_bounds__(BT, 8) squant_kernel(const float* __restrict__ x,
                                                       float* __restrict__ out,
                                                       const float* __restrict__ part,
                                                       int nparts) {
    __shared__ __align__(16) unsigned char s_mem[CH * 4];  // 36 KB
    __shared__ float s_mx[8];
    float* s_x   = (float*)s_mem;
    short* s_q   = (short*)s_mem;                  // bytes [0, 18432)
    float* s_res = (float*)(s_mem + 18432);        // [18432, 22528)
    float* s_pr  = (float*)(s_mem + 22528);        // [22528, 26624)
    int*   s_me  = (int*)(s_mem + 26624);          // [26624, 30720)

    const int oc = blockIdx.x;
    const int t  = threadIdx.x;
    const long long ocbase = (long long)oc * CH;

    // ---- stage-in (coalesced) + scale reduce, one barrier ----
    const float4* x4 = (const float4*)(x + ocbase);
    float4* s4 = (float4*)s_mem;
    #pragma unroll
    for (int k = 0; k < 4; ++k) s4[t + BT * k] = x4[t + BT * k];
    if (t < CH4 - 4 * BT) s4[4 * BT + t] = x4[4 * BT + t];

    if (nparts > 0) {
        float m = fmaxf(fmaxf(part[t], part[t + BT]),
                        fmaxf(part[t + 2 * BT], part[t + 3 * BT]));
        #pragma unroll
        for (int off = 32; off > 0; off >>= 1)
            m = fmaxf(m, __shfl_xor(m, off, 64));
        if ((t & 63) == 0) s_mx[t >> 6] = m;
    } else if (t == 0) {
        s_mx[0] = __uint_as_float(((const unsigned*)part)[0]);
        #pragma unroll
        for (int w = 1; w < 8; ++w) s_mx[w] = s_mx[0];
    }
    __syncthreads();
    float gm = s_mx[0];
    if (nparts > 0) {
        #pragma unroll
        for (int w = 1; w < 8; ++w) gm = fmaxf(gm, s_mx[w]);
    }
    const float scale = gm / 127.0f;
    const float iscale = 1.0f / scale;  // mul not div: verified bit-identical (R3/R4 absmax 0.0)

    // ---- stage 1 from LDS floats; results held in registers ----
    float rn2[2][KK];
    unsigned flip2[2];
    float res2[2], pr2[2], sg2[2];
    int me2[2];
    #pragma unroll
    for (int half = 0; half < 2; ++half) {
        const int row = t + half * BT;
        float re[KK];
        float e = 0.f;
        #pragma unroll
        for (int k = 0; k < KK; ++k) {
            float q = s_x[row * KK + k] * iscale;   // stride-9 dwords: 2 lanes/bank, free
            q = fminf(fmaxf(q, -127.f), 127.f);
            float r = rintf(q);                     // round half to even
            rn2[half][k] = r;
            re[k] = r - q;
            e += re[k];
        }
        int nf = (int)rintf(fabsf(e));
        bool up = e < 0.f;
        unsigned flipped = 0u;
        int bidx = -1;
        float b_re = 0.f;
        for (int f = 0; f < nf; ++f) {
            float bp = 0.f; int bk = -1; float cre = 0.f;
            #pragma unroll
            for (int k = 0; k < KK; ++k) {
                bool cand = up ? (re[k] < 0.f) : (re[k] > 0.f);
                float p = (cand && !((flipped >> k) & 1u)) ? fabsf(re[k]) : 0.f;
                if (p > bp) { bp = p; bk = k; cre = re[k]; }  // strict >: lowest idx wins ties
            }
            if (bk < 0) break;  // safety
            flipped |= (1u << bk);
            bidx = bk; b_re = cre;
        }
        float sgn = up ? 1.f : -1.f;
        flip2[half] = flipped;
        sg2[half] = sgn;
        res2[half] = e + sgn * (float)__popc(flipped);
        if (bidx >= 0) {
            pr2[half] = fabsf(b_re + sgn);
            me2[half] = (row * KK + bidx) | ((up ? 1 : 0) << 16);
        } else {
            pr2[half] = 0.f;
            me2[half] = 0;
        }
    }
    __syncthreads();  // all x reads done before the overlay is clobbered

    #pragma unroll
    for (int half = 0; half < 2; ++half) {
        const int row = t + half * BT;
        #pragma unroll
        for (int k = 0; k < KK; ++k)
            s_q[row * KK + k] =
                (short)(int)(rn2[half][k] + (((flip2[half] >> k) & 1u) ? sg2[half] : 0.f));
        s_res[row] = res2[half];
        s_pr[row]  = pr2[half];
        s_me[row]  = me2[half];
    }
    __syncthreads();

    // ---- stage 2: wave 0 only ----
    if (t < 64) {
        float s = 0.f;
        #pragma unroll
        for (int i = 0; i < ICN / 64; ++i) s += s_res[t + i * 64];
        #pragma unroll
        for (int off = 32; off > 0; off >>= 1) s += __shfl_xor(s, off, 64);

        int n2 = (int)rintf(fabsf(s));
        bool up2 = s < 0.f;
        if (n2 > 0) {
            float p[ICN / 64];
            #pragma unroll
            for (int i = 0; i < ICN / 64; ++i) {
                int r = t + i * 64;
                float pr = s_pr[r];
                int dir = s_me[r] >> 16;             // 1: row flipped up -> stage-2 down candidate
                bool match = ((dir != 0) != up2);
                p[i] = (pr > 0.f && match) ? pr : 0.f;
            }
            int f = 0;
            for (; f < n2; ++f) {
                float bp = 0.f; int brow = ICN;      // ICN loses all index ties
                #pragma unroll
                for (int i = 0; i < ICN / 64; ++i)
                    if (p[i] > bp) { bp = p[i]; brow = t + i * 64; }
                #pragma unroll
                for (int off = 32; off > 0; off >>= 1) {
                    float op = __shfl_xor(bp, off, 64);
                    int  orow = __shfl_xor(brow, off, 64);
                    if (op > bp || (op == bp && orow < brow)) { bp = op; brow = orow; }
                }
                if (bp <= 0.f) break;  // exhausted -> fallback
                if (t == (brow & 63)) {
                    #pragma unroll
                    for (int i = 0; i < ICN / 64; ++i)
                        if (i == (brow >> 6)) p[i] = 0.f;
                }
                if (t == 0) {
                    int meta = s_me[brow];
                    int gid = meta & 0xFFFF;
                    s_q[gid] = (short)(s_q[gid] + ((meta >> 16) ? -1 : 1));  // revert boundary
                }
            }
            if (f < n2) {  // dead overflow path; deviation <= 1 step
                int remaining = n2 - f;
                if (remaining > CH) remaining = CH;
                for (int j = t; j < remaining; j += 64) {
                    float q = x[ocbase + j] * iscale;
                    q = fminf(fmaxf(q, -127.f), 127.f);
                    float r = rintf(q);
                    float rr = r - q;
                    float v = up2 ? ((rr < 0.f) ? r + 1.f : r)
                                  : ((rr > 0.f) ? r - 1.f : r);
                    s_q[j] = (short)(int)v;
                }
            }
        }
    }
    __syncthreads();

    // ---- coalesced stage-out: s16 -> f32*scale ----
    const short4* q4 = (const short4*)s_mem;
    float4* o4 = (float4*)(out + ocbase);
    #pragma unroll
    for (int k = 0; k < 4; ++k) {
        short4 v = q4[t + BT * k];
        float4 o;
        o.x = (float)v.x * scale;
        o.y = (float)v.y * scale;
        o.z = (float)v.z * scale;
        o.w = (float)v.w * scale;
        o4[t + BT * k] = o;
    }
    if (t < CH4 - 4 * BT) {
        short4 v = q4[4 * BT + t];
        float4 o;
        o.x = (float)v.x * scale;
        o.y = (float)v.y * scale;
        o.z = (float)v.z * scale;
        o.w = (float)v.w * scale;
        o4[4 * BT + t] = o;
    }
}

extern "C" void kernel_launch(void* const* d_in, const int* in_sizes, int n_in,
                              void* d_out, int out_size, void* d_ws, size_t ws_size,
                              hipStream_t stream) {
    const float* x = (const float*)d_in[0];
    float* out = (float*)d_out;
    if (ws_size >= KMB * sizeof(float)) {
        float* part = (float*)d_ws;
        kmax_part<<<KMB, 256, 0, stream>>>(x, part);
        squant_kernel<<<OC, BT, 0, stream>>>(x, out, part, KMB);
    } else {
        unsigned* wsmax = (unsigned*)d_ws;
        hipMemsetAsync(d_ws, 0, 4, stream);  // ws re-poisoned 0xAA each launch
        kmax_atomic<<<KMB, 256, 0, stream>>>(x, wsmax);
        squant_kernel<<<OC, BT, 0, stream>>>(x, out, (const float*)d_ws, 0);
    }
}